// Round 5
// baseline (466.379 us; speedup 1.0000x reference)
//
#include <hip/hip_runtime.h>
#include <stdint.h>

#define STEP 0.02f
#define INV_RADIUS (1.0f/1.3f)
#define RADIUS 1.3f

typedef __bf16 bf16x8 __attribute__((ext_vector_type(8)));
typedef float  f32x4  __attribute__((ext_vector_type(4)));

// ---------------- ws layout (bytes) ----------------
#define FT_OFF   0         // F transposed bf16 [z16][y16][x16][c32] = 262144 B
#define W0_OFF   262144    // sig W0  K=32  N=128 : 1kk x 8nt  = 8192 B
#define W1_OFF   270336    // sig W1  K=128 N=128 : 4kk x 8nt  = 32768 B
#define W2_OFF   303104    // sig W2  K=128 N=16  : 4kk x 1nt  = 4096 B
#define C0_OFF   307200    // col W0  K=31->32 N=64 : 1x4      = 4096 B
#define C1_OFF   311296    // col W1  K=64 N=64 : 2x4          = 8192 B
#define C2_OFF   319488    // col W2  K=64 N=3->16 : 2x1       = 2048 B (end 321536)

// ---------------- per-wave LDS region (bytes) ----------------
// wave-private: no __syncthreads anywhere in nerf_fused.
#define FE_OFF    0        // feats 64 rows x 64B = 4096
#define HA_OFF    4096     // hidden A: up to 4kk x 16 rows x 64B = 4096
#define HB_OFF    8192     // hidden B: 4096
#define CIN_OFF   12288    // color-in 16 rows x 64B = 1024
#define SIG_OFF   13312    // 128 f32 = 512
#define COL_OFF   13824    // 128 x 4 f32 = 2048
#define WAVE_LDS  15872    // per wave; x4 waves = 63488 B/block -> 2 blocks/CU (LDS-bound)

__device__ __forceinline__ uint32_t pack2(float a, float b){
    uint32_t ua = __float_as_uint(a); ua += 0x7FFFu + ((ua>>16)&1u);
    uint32_t ub = __float_as_uint(b); ub += 0x7FFFu + ((ub>>16)&1u);
    return (ua>>16) | (ub & 0xFFFF0000u);
}
__device__ __forceinline__ unsigned short f2bf(float f){
    uint32_t u = __float_as_uint(f); u += 0x7FFFu + ((u>>16)&1u);
    return (unsigned short)(u>>16);
}
__device__ __forceinline__ void toidx(float c, float sizem1, int isize,
                                      int& i0, int& i1, float& w){
    float t = (c + 1.f) * 0.5f * sizem1;
    t = fminf(fmaxf(t, 0.f), sizem1);
    float f = floorf(t);
    i0 = (int)f;
    i1 = i0 + 1; if (i1 > isize - 1) i1 = isize - 1;
    w = t - f;
}
// wave-internal LDS fence: all prior ds_writes visible to subsequent ds_reads
// (cross-lane within one wave). "memory" clobber pins compiler ordering.
__device__ __forceinline__ void lds_fence(){
    asm volatile("s_waitcnt lgkmcnt(0)" ::: "memory");
}

// ---------------- prep: transpose F (32,16,16,16) -> bf16 [z][y][x][c] ----------------
__global__ __launch_bounds__(256) void prep_f(const float* __restrict__ F, uint32_t* __restrict__ ws){
    int idx = blockIdx.x * 256 + threadIdx.x;   // 0..4095 spatial cells
    if (idx >= 4096) return;
    uint32_t out[16];
    #pragma unroll
    for (int c = 0; c < 16; c++){
        float a = F[(2*c  )*4096 + idx];
        float b = F[(2*c+1)*4096 + idx];
        out[c] = pack2(a, b);
    }
    uint4* dst = (uint4*)ws;   // FT_OFF == 0
    #pragma unroll
    for (int q = 0; q < 4; q++)
        dst[idx*4 + q] = make_uint4(out[q*4], out[q*4+1], out[q*4+2], out[q*4+3]);
}

// ---------------- prep: weights -> bf16 MFMA B-fragment layout ----------------
// chunk (kk,nt): lane l holds B[k = kk*32 + (l>>4)*8 + j][n = nt*16 + (l&15)], j=0..7 (16B)
__global__ __launch_bounds__(256) void prep_w(const float* __restrict__ W0, const float* __restrict__ W1,
                                              const float* __restrict__ W2, const float* __restrict__ Wc0,
                                              const float* __restrict__ Wc1, const float* __restrict__ Wc2,
                                              char* __restrict__ ws){
    int gid = blockIdx.x * 256 + threadIdx.x;
    if (gid >= 58*64) return;
    int cg = gid >> 6, lane = gid & 63;
    const float* src; int K, N, base_cg, dstoff;
    if      (cg < 8)  { src = W0;  K = 32;  N = 128; base_cg = 0;  dstoff = W0_OFF; }
    else if (cg < 40) { src = W1;  K = 128; N = 128; base_cg = 8;  dstoff = W1_OFF; }
    else if (cg < 44) { src = W2;  K = 128; N = 16;  base_cg = 40; dstoff = W2_OFF; }
    else if (cg < 48) { src = Wc0; K = 31;  N = 64;  base_cg = 44; dstoff = C0_OFF; }
    else if (cg < 56) { src = Wc1; K = 64;  N = 64;  base_cg = 48; dstoff = C1_OFF; }
    else              { src = Wc2; K = 64;  N = 3;   base_cg = 56; dstoff = C2_OFF; }
    int local = cg - base_cg;
    int NT = (N + 15) >> 4;
    int nt = local % NT, kk = local / NT;
    int n = nt*16 + (lane & 15);
    int kbase = kk*32 + (lane >> 4)*8;
    uint32_t o[4];
    #pragma unroll
    for (int jj = 0; jj < 4; jj++){
        int k0 = kbase + jj*2, k1 = k0 + 1;
        float a = (n < N && k0 < K) ? src[k0*N + n] : 0.f;
        float b = (n < N && k1 < K) ? src[k1*N + n] : 0.f;
        o[jj] = pack2(a, b);
    }
    uint4* dst = (uint4*)(ws + dstoff);
    dst[local*64 + lane] = make_uint4(o[0], o[1], o[2], o[3]);
}

// ---------------- fused main: one WAVE per ray, no block barriers ----------------
__global__ __launch_bounds__(256)
void nerf_fused(const float* __restrict__ rays_o, const float* __restrict__ rays_d,
                const float* __restrict__ G1, const char* __restrict__ ws,
                float* __restrict__ out){
    __shared__ __align__(16) char smem[WAVE_LDS*4];
    const int tid  = threadIdx.x;
    const int wv   = tid >> 6;
    const int lane = tid & 63;
    const int nl   = lane & 15;
    const int quad = lane >> 4;
    const int ray  = blockIdx.x*4 + wv;
    char* WB = smem + wv*WAVE_LDS;

    // ---- ray setup (uniform per wave) ----
    float ox = rays_o[ray*3+0], oy = rays_o[ray*3+1], oz = rays_o[ray*3+2];
    float rx = rays_d[ray*3+0], ry = rays_d[ray*3+1], rz = rays_d[ray*3+2];
    float nrm = sqrtf(rx*rx + ry*ry + rz*rz);
    float dx = rx/nrm, dy = ry/nrm, dz = rz/nrm;
    float bq = ox*dx + oy*dy + oz*dz;
    float cq = ox*ox + oy*oy + oz*oz - RADIUS*RADIUS;
    float disc = bq*bq - cq;
    bool  hit = disc > 0.f;
    float sq   = sqrtf(hit ? disc : 1.f);
    float tmin = hit ? fmaxf(-bq - sq, 0.f) : 0.f;
    float tmax = hit ? (-bq + sq) : 0.f;

    // ---- SH enc of ray dir -> CIN rows 0..15, chunks 0,1 (once per ray) ----
    {
        float X=dx, Y=dy, Z=dz;
        float xx=X*X, yy=Y*Y, zz=Z*Z, xy=X*Y, yz=Y*Z, xz=X*Z;
        float e[16];
        e[0]=0.28209479177387814f;
        e[1]=-0.48860251190291987f*Y;
        e[2]= 0.48860251190291987f*Z;
        e[3]=-0.48860251190291987f*X;
        e[4]= 1.0925484305920792f*xy;
        e[5]=-1.0925484305920792f*yz;
        e[6]= 0.94617469575756f*zz - 0.31539156525252f;
        e[7]=-1.0925484305920792f*xz;
        e[8]= 0.5462742152960396f*(xx-yy);
        e[9]= 0.5900435899266435f*Y*(-3.f*xx+yy);
        e[10]=2.890611442640554f*xy*Z;
        e[11]=0.4570457994644657f*Y*(1.f-5.f*zz);
        e[12]=0.3731763325901154f*Z*(5.f*zz-3.f);
        e[13]=0.4570457994644657f*X*(1.f-5.f*zz);
        e[14]=1.445305721320277f*Z*(xx-yy);
        e[15]=0.5900435899266435f*X*(-xx+3.f*yy);
        int rsw = (nl>>1)&3;
        if (quad < 2){
            uint4 v = make_uint4(pack2(e[quad*8+0], e[quad*8+1]),
                                 pack2(e[quad*8+2], e[quad*8+3]),
                                 pack2(e[quad*8+4], e[quad*8+5]),
                                 pack2(e[quad*8+6], e[quad*8+7]));
            *(uint4*)(WB + CIN_OFF + nl*64 + ((quad ^ rsw)*16)) = v;
        } else if (quad == 3){
            *(unsigned short*)(WB + CIN_OFF + nl*64 + ((3 ^ rsw)*16) + 14) = 0;  // k=31 pad
        }
    }

    const char* pW0 = ws + W0_OFF; const char* pW1 = ws + W1_OFF; const char* pW2 = ws + W2_OFF;
    const char* pC0 = ws + C0_OFF; const char* pC1 = ws + C1_OFF; const char* pC2 = ws + C2_OFF;
    const f32x4 vzero = {0.f, 0.f, 0.f, 0.f};
    float* SIGf = (float*)(WB + SIG_OFF);
    float* COLf = (float*)(WB + COL_OFF);

    #define RD_A(bp, linRow, m) \
        (*(const bf16x8*)((bp) + (linRow)*64 + ((quad ^ (((m)>>1)&3))*16)))
    #define LD_B(base, kk, NT, nt) \
        (*(const bf16x8*)((base) + (((kk)*(NT) + (nt))*64 + lane)*16))
    #define WR_H(bp, ROWS, m, kpos, val) \
        *(unsigned short*)((bp) + (((kpos)>>5)*(ROWS) + (m))*64 \
            + (((((kpos)>>3)&3) ^ (((m)>>1)&3))*16) + ((kpos)&7)*2) = f2bf(val)

    for (int half = 0; half < 2; half++){
        // ---- gather: this lane fully gathers sample p = half*64+lane ----
        {
            int p = half*64 + lane;
            float tmid = tmin + ((float)p + 0.5f) * STEP;
            float px = (ox + dx*tmid) * INV_RADIUS;
            float py = (oy + dy*tmid) * INV_RADIUS;
            float pz = (oz + dz*tmid) * INV_RADIUS;
            int x0,x1,y0,y1,z0,z1; float wx,wy,wz;
            toidx(px, 255.f, 256, x0, x1, wx);
            toidx(py, 255.f, 256, y0, y1, wy);
            toidx(pz, 255.f, 256, z0, z1, wz);
            float g1v[3];
            #pragma unroll
            for (int ch = 0; ch < 3; ch++){
                const float* gp = G1 + ch*16777216;
                int b00 = (z0*256 + y0)*256, b01 = (z0*256 + y1)*256;
                int b10 = (z1*256 + y0)*256, b11 = (z1*256 + y1)*256;
                float c000 = gp[b00+x0], c001 = gp[b00+x1];
                float c010 = gp[b01+x0], c011 = gp[b01+x1];
                float c100 = gp[b10+x0], c101 = gp[b10+x1];
                float c110 = gp[b11+x0], c111 = gp[b11+x1];
                float c00 = c000 + (c001-c000)*wx;
                float c01 = c010 + (c011-c010)*wx;
                float c10 = c100 + (c101-c100)*wx;
                float c11 = c110 + (c111-c110)*wx;
                float c0 = c00 + (c01-c00)*wy;
                float c1 = c10 + (c11-c10)*wy;
                g1v[ch] = c0 + (c1-c0)*wz;
            }
            int fx0,fx1,fy0,fy1,fz0,fz1; float fwx,fwy,fwz;
            toidx(g1v[0], 15.f, 16, fx0, fx1, fwx);
            toidx(g1v[1], 15.f, 16, fy0, fy1, fwy);
            toidx(g1v[2], 15.f, 16, fz0, fz1, fwz);
            float feats[32];
            #pragma unroll
            for (int i = 0; i < 32; i++) feats[i] = 0.f;
            const uint4* Ft = (const uint4*)(ws + FT_OFF);
            // unroll 2: max 8 uint4 loads (32 VGPRs) in flight -> no spill
            #pragma unroll 2
            for (int corner = 0; corner < 8; corner++){
                int cz = (corner>>2)&1, cy = (corner>>1)&1, cx = corner&1;
                int xi = cx?fx1:fx0, yi = cy?fy1:fy0, zi = cz?fz1:fz0;
                float w = (cx?fwx:1.f-fwx) * (cy?fwy:1.f-fwy) * (cz?fwz:1.f-fwz);
                const uint4* cp = Ft + ((zi*16 + yi)*16 + xi)*4;
                #pragma unroll
                for (int q = 0; q < 4; q++){
                    uint4 v = cp[q];
                    uint32_t u[4] = {v.x, v.y, v.z, v.w};
                    #pragma unroll
                    for (int e = 0; e < 4; e++){
                        feats[q*8 + e*2    ] += w * __uint_as_float(u[e] << 16);
                        feats[q*8 + e*2 + 1] += w * __uint_as_float(u[e] & 0xFFFF0000u);
                    }
                }
            }
            int fsw = (lane>>1)&3;
            #pragma unroll
            for (int c = 0; c < 4; c++){
                uint4 v = make_uint4(pack2(feats[c*8+0], feats[c*8+1]),
                                     pack2(feats[c*8+2], feats[c*8+3]),
                                     pack2(feats[c*8+4], feats[c*8+5]),
                                     pack2(feats[c*8+6], feats[c*8+7]));
                *(uint4*)(WB + FE_OFF + lane*64 + ((c^fsw)*16)) = v;
            }
        }
        lds_fence();

        // ---- MLP: 4 tiles of 16 samples, wave-private, fence-ordered ----
        for (int mt = 0; mt < 4; mt++){
            const int mArow = mt*16 + nl;
            const int mW = quad*4;                       // tile-local row base
            const int gRow = half*64 + mt*16 + mW;       // ray-local sample row base

            { // L0: feats[16,32] @ W0 -> HA[16,128], relu
                bf16x8 a = RD_A(WB + FE_OFF, mArow, mArow);
                f32x4 acc[8];
                #pragma unroll
                for (int nt = 0; nt < 8; nt++){
                    bf16x8 b = LD_B(pW0, 0, 8, nt);
                    acc[nt] = __builtin_amdgcn_mfma_f32_16x16x32_bf16(a, b, vzero, 0, 0, 0);
                }
                #pragma unroll
                for (int nt = 0; nt < 8; nt++)
                    #pragma unroll
                    for (int r = 0; r < 4; r++)
                        WR_H(WB + HA_OFF, 16, mW + r, nt*16 + nl, fmaxf(acc[nt][r], 0.f));
            }
            lds_fence();
            { // L1: HA @ W1 -> HB[16,128], relu
                f32x4 acc[8];
                #pragma unroll
                for (int nt = 0; nt < 8; nt++) acc[nt] = vzero;
                #pragma unroll
                for (int kk = 0; kk < 4; kk++){
                    bf16x8 a = RD_A(WB + HA_OFF, kk*16 + nl, nl);
                    #pragma unroll
                    for (int nt = 0; nt < 8; nt++){
                        bf16x8 b = LD_B(pW1, kk, 8, nt);
                        acc[nt] = __builtin_amdgcn_mfma_f32_16x16x32_bf16(a, b, acc[nt], 0, 0, 0);
                    }
                }
                #pragma unroll
                for (int nt = 0; nt < 8; nt++)
                    #pragma unroll
                    for (int r = 0; r < 4; r++)
                        WR_H(WB + HB_OFF, 16, mW + r, nt*16 + nl, fmaxf(acc[nt][r], 0.f));
            }
            lds_fence();
            { // L2: HB @ W2 -> sig_out[16,16]; n=0 -> SIG, n>=1 -> CIN k=15+n
                f32x4 acc = vzero;
                #pragma unroll
                for (int kk = 0; kk < 4; kk++){
                    bf16x8 a = RD_A(WB + HB_OFF, kk*16 + nl, nl);
                    bf16x8 b = LD_B(pW2, kk, 1, 0);
                    acc = __builtin_amdgcn_mfma_f32_16x16x32_bf16(a, b, acc, 0, 0, 0);
                }
                #pragma unroll
                for (int r = 0; r < 4; r++){
                    float v = acc[r];
                    if (nl == 0) SIGf[gRow + r] = v;
                    else         WR_H(WB + CIN_OFF, 16, mW + r, 15 + nl, v);
                }
            }
            lds_fence();
            { // C0: CIN[16,32] @ Wc0 -> HA[16,64], relu
                bf16x8 a = RD_A(WB + CIN_OFF, nl, nl);
                f32x4 acc[4];
                #pragma unroll
                for (int nt = 0; nt < 4; nt++){
                    bf16x8 b = LD_B(pC0, 0, 4, nt);
                    acc[nt] = __builtin_amdgcn_mfma_f32_16x16x32_bf16(a, b, vzero, 0, 0, 0);
                }
                #pragma unroll
                for (int nt = 0; nt < 4; nt++)
                    #pragma unroll
                    for (int r = 0; r < 4; r++)
                        WR_H(WB + HA_OFF, 16, mW + r, nt*16 + nl, fmaxf(acc[nt][r], 0.f));
            }
            lds_fence();
            { // C1: HA[16,64] @ Wc1 -> HB[16,64], relu
                f32x4 acc[4];
                #pragma unroll
                for (int nt = 0; nt < 4; nt++) acc[nt] = vzero;
                #pragma unroll
                for (int kk = 0; kk < 2; kk++){
                    bf16x8 a = RD_A(WB + HA_OFF, kk*16 + nl, nl);
                    #pragma unroll
                    for (int nt = 0; nt < 4; nt++){
                        bf16x8 b = LD_B(pC1, kk, 4, nt);
                        acc[nt] = __builtin_amdgcn_mfma_f32_16x16x32_bf16(a, b, acc[nt], 0, 0, 0);
                    }
                }
                #pragma unroll
                for (int nt = 0; nt < 4; nt++)
                    #pragma unroll
                    for (int r = 0; r < 4; r++)
                        WR_H(WB + HB_OFF, 16, mW + r, nt*16 + nl, fmaxf(acc[nt][r], 0.f));
            }
            lds_fence();
            { // C2: HB[16,64] @ Wc2 -> col[16,3]
                f32x4 acc = vzero;
                #pragma unroll
                for (int kk = 0; kk < 2; kk++){
                    bf16x8 a = RD_A(WB + HB_OFF, kk*16 + nl, nl);
                    bf16x8 b = LD_B(pC2, kk, 1, 0);
                    acc = __builtin_amdgcn_mfma_f32_16x16x32_bf16(a, b, acc, 0, 0, 0);
                }
                #pragma unroll
                for (int r = 0; r < 4; r++)
                    if (nl < 3) COLf[(gRow + r)*4 + nl] = acc[r];
            }
            lds_fence();
        }
    }

    // ---- composite: per-wave scan over 128 samples (2 per lane) ----
    float t0 = tmin + ((float)lane + 0.5f) * STEP;
    float t1 = tmin + ((float)(lane + 64) + 0.5f) * STEP;
    bool  m0 = hit && (t0 <= tmax);
    bool  m1 = hit && (t1 <= tmax);
    float sig0 = m0 ? fmaxf(SIGf[lane], 0.f) : 0.f;
    float sig1 = m1 ? fmaxf(SIGf[lane + 64], 0.f) : 0.f;
    float e0 = expf(-sig0 * STEP), e1 = expf(-sig1 * STEP);
    float al0 = 1.f - e0, al1 = 1.f - e1;
    float li0 = logf(e0 + 1e-10f), li1 = logf(e1 + 1e-10f);
    float incl0 = li0, incl1 = li1;
    #pragma unroll
    for (int off = 1; off < 64; off <<= 1){
        float v0 = __shfl_up(incl0, off);
        float v1 = __shfl_up(incl1, off);
        if (lane >= off){ incl0 += v0; incl1 += v1; }
    }
    float tot0 = __shfl(incl0, 63);
    float ex0 = incl0 - li0;
    float ex1 = tot0 + incl1 - li1;
    float w0 = al0 * expf(ex0);
    float w1 = al1 * expf(ex1);
    float r = w0 / (1.f + expf(-COLf[lane*4+0])) + w1 / (1.f + expf(-COLf[(lane+64)*4+0]));
    float g = w0 / (1.f + expf(-COLf[lane*4+1])) + w1 / (1.f + expf(-COLf[(lane+64)*4+1]));
    float b = w0 / (1.f + expf(-COLf[lane*4+2])) + w1 / (1.f + expf(-COLf[(lane+64)*4+2]));
    float wa = w0 + w1;
    #pragma unroll
    for (int off = 32; off > 0; off >>= 1){
        r  += __shfl_xor(r,  off);
        g  += __shfl_xor(g,  off);
        b  += __shfl_xor(b,  off);
        wa += __shfl_xor(wa, off);
    }
    if (lane == 0){
        out[ray*3+0] = r + (1.f - wa);
        out[ray*3+1] = g + (1.f - wa);
        out[ray*3+2] = b + (1.f - wa);
    }
}

extern "C" void kernel_launch(void* const* d_in, const int* in_sizes, int n_in,
                              void* d_out, int out_size, void* d_ws, size_t ws_size,
                              hipStream_t stream){
    const float* rays_o = (const float*)d_in[0];
    const float* rays_d = (const float*)d_in[1];
    const float* G1     = (const float*)d_in[2];
    const float* F      = (const float*)d_in[3];
    prep_f<<<16, 256, 0, stream>>>(F, (uint32_t*)d_ws);
    prep_w<<<15, 256, 0, stream>>>((const float*)d_in[4], (const float*)d_in[5],
                                   (const float*)d_in[6], (const float*)d_in[7],
                                   (const float*)d_in[8], (const float*)d_in[9],
                                   (char*)d_ws);
    nerf_fused<<<1024, 256, 0, stream>>>(rays_o, rays_d, G1, (const char*)d_ws, (float*)d_out);
}

// Round 6
// 445.065 us; speedup vs baseline: 1.0479x; 1.0479x over previous
//
#include <hip/hip_runtime.h>
#include <stdint.h>

#define STEP 0.02f
#define INV_RADIUS (1.0f/1.3f)
#define RADIUS 1.3f

typedef __bf16 bf16x8 __attribute__((ext_vector_type(8)));
typedef float  f32x4  __attribute__((ext_vector_type(4)));

// ---------------- ws layout (bytes) ----------------
#define FT_OFF   0         // F transposed bf16 [z16][y16][x16][c32] = 262144 B
#define W0_OFF   262144    // sig W0  K=32  N=128 : 1kk x 8nt  = 8192 B
#define W1_OFF   270336    // sig W1  K=128 N=128 : 4kk x 8nt  = 32768 B
#define W2_OFF   303104    // sig W2  K=128 N=16  : 4kk x 1nt  = 4096 B
#define C0_OFF   307200    // col W0  K=31->32 N=64 : 1x4      = 4096 B
#define C1_OFF   311296    // col W1  K=64 N=64 : 2x4          = 8192 B
#define C2_OFF   319488    // col W2  K=64 N=3->16 : 2x1       = 2048 B (end 321536)

// ---------------- per-wave LDS region (bytes) ----------------
// wave-private: no __syncthreads anywhere in nerf_fused.
#define FE_OFF    0        // feats 64 rows x 64B = 4096
#define HA_OFF    4096     // hidden A: up to 4kk x 16 rows x 64B = 4096
#define HB_OFF    8192     // hidden B: 4096
#define CIN_OFF   12288    // color-in 16 rows x 64B = 1024
#define SIG_OFF   13312    // 128 f32 = 512
#define COL_OFF   13824    // 128 x 4 f32 = 2048
#define WAVE_LDS  15872    // per wave; x4 waves = 63488 B/block -> 2 blocks/CU (LDS-bound)

__device__ __forceinline__ uint32_t pack2(float a, float b){
    uint32_t ua = __float_as_uint(a); ua += 0x7FFFu + ((ua>>16)&1u);
    uint32_t ub = __float_as_uint(b); ub += 0x7FFFu + ((ub>>16)&1u);
    return (ua>>16) | (ub & 0xFFFF0000u);
}
__device__ __forceinline__ unsigned short f2bf(float f){
    uint32_t u = __float_as_uint(f); u += 0x7FFFu + ((u>>16)&1u);
    return (unsigned short)(u>>16);
}
__device__ __forceinline__ void toidx(float c, float sizem1, int isize,
                                      int& i0, int& i1, float& w){
    float t = (c + 1.f) * 0.5f * sizem1;
    t = fminf(fmaxf(t, 0.f), sizem1);
    float f = floorf(t);
    i0 = (int)f;
    i1 = i0 + 1; if (i1 > isize - 1) i1 = isize - 1;
    w = t - f;
}
// wave-internal LDS fence: all prior ds_writes visible to subsequent ds_reads
// (cross-lane within one wave). "memory" clobber pins compiler ordering for
// MEMORY accesses only — named locals (register-resident B-frags) survive it.
__device__ __forceinline__ void lds_fence(){
    asm volatile("s_waitcnt lgkmcnt(0)" ::: "memory");
}

// ---------------- prep: transpose F (32,16,16,16) -> bf16 [z][y][x][c] ----------------
__global__ __launch_bounds__(256) void prep_f(const float* __restrict__ F, uint32_t* __restrict__ ws){
    int idx = blockIdx.x * 256 + threadIdx.x;   // 0..4095 spatial cells
    if (idx >= 4096) return;
    uint32_t out[16];
    #pragma unroll
    for (int c = 0; c < 16; c++){
        float a = F[(2*c  )*4096 + idx];
        float b = F[(2*c+1)*4096 + idx];
        out[c] = pack2(a, b);
    }
    uint4* dst = (uint4*)ws;   // FT_OFF == 0
    #pragma unroll
    for (int q = 0; q < 4; q++)
        dst[idx*4 + q] = make_uint4(out[q*4], out[q*4+1], out[q*4+2], out[q*4+3]);
}

// ---------------- prep: weights -> bf16 MFMA B-fragment layout ----------------
// chunk (kk,nt): lane l holds B[k = kk*32 + (l>>4)*8 + j][n = nt*16 + (l&15)], j=0..7 (16B)
__global__ __launch_bounds__(256) void prep_w(const float* __restrict__ W0, const float* __restrict__ W1,
                                              const float* __restrict__ W2, const float* __restrict__ Wc0,
                                              const float* __restrict__ Wc1, const float* __restrict__ Wc2,
                                              char* __restrict__ ws){
    int gid = blockIdx.x * 256 + threadIdx.x;
    if (gid >= 58*64) return;
    int cg = gid >> 6, lane = gid & 63;
    const float* src; int K, N, base_cg, dstoff;
    if      (cg < 8)  { src = W0;  K = 32;  N = 128; base_cg = 0;  dstoff = W0_OFF; }
    else if (cg < 40) { src = W1;  K = 128; N = 128; base_cg = 8;  dstoff = W1_OFF; }
    else if (cg < 44) { src = W2;  K = 128; N = 16;  base_cg = 40; dstoff = W2_OFF; }
    else if (cg < 48) { src = Wc0; K = 31;  N = 64;  base_cg = 44; dstoff = C0_OFF; }
    else if (cg < 56) { src = Wc1; K = 64;  N = 64;  base_cg = 48; dstoff = C1_OFF; }
    else              { src = Wc2; K = 64;  N = 3;   base_cg = 56; dstoff = C2_OFF; }
    int local = cg - base_cg;
    int NT = (N + 15) >> 4;
    int nt = local % NT, kk = local / NT;
    int n = nt*16 + (lane & 15);
    int kbase = kk*32 + (lane >> 4)*8;
    uint32_t o[4];
    #pragma unroll
    for (int jj = 0; jj < 4; jj++){
        int k0 = kbase + jj*2, k1 = k0 + 1;
        float a = (n < N && k0 < K) ? src[k0*N + n] : 0.f;
        float b = (n < N && k1 < K) ? src[k1*N + n] : 0.f;
        o[jj] = pack2(a, b);
    }
    uint4* dst = (uint4*)(ws + dstoff);
    dst[local*64 + lane] = make_uint4(o[0], o[1], o[2], o[3]);
}

// ---------------- fused main: one WAVE per ray, no block barriers ----------------
__global__ __launch_bounds__(256, 2)
void nerf_fused(const float* __restrict__ rays_o, const float* __restrict__ rays_d,
                const float* __restrict__ G1, const char* __restrict__ ws,
                float* __restrict__ out){
    __shared__ __align__(16) char smem[WAVE_LDS*4];
    const int tid  = threadIdx.x;
    const int wv   = tid >> 6;
    const int lane = tid & 63;
    const int nl   = lane & 15;
    const int quad = lane >> 4;
    const int ray  = blockIdx.x*4 + wv;
    char* WB = smem + wv*WAVE_LDS;

    // ---- ray setup (uniform per wave) ----
    float ox = rays_o[ray*3+0], oy = rays_o[ray*3+1], oz = rays_o[ray*3+2];
    float rx = rays_d[ray*3+0], ry = rays_d[ray*3+1], rz = rays_d[ray*3+2];
    float nrm = sqrtf(rx*rx + ry*ry + rz*rz);
    float dx = rx/nrm, dy = ry/nrm, dz = rz/nrm;
    float bq = ox*dx + oy*dy + oz*dz;
    float cq = ox*ox + oy*oy + oz*oz - RADIUS*RADIUS;
    float disc = bq*bq - cq;
    bool  hit = disc > 0.f;
    float sq   = sqrtf(hit ? disc : 1.f);
    float tmin = hit ? fmaxf(-bq - sq, 0.f) : 0.f;
    float tmax = hit ? (-bq + sq) : 0.f;

    // ---- SH enc of ray dir -> CIN rows 0..15, chunks 0,1 (once per ray) ----
    {
        float X=dx, Y=dy, Z=dz;
        float xx=X*X, yy=Y*Y, zz=Z*Z, xy=X*Y, yz=Y*Z, xz=X*Z;
        float e[16];
        e[0]=0.28209479177387814f;
        e[1]=-0.48860251190291987f*Y;
        e[2]= 0.48860251190291987f*Z;
        e[3]=-0.48860251190291987f*X;
        e[4]= 1.0925484305920792f*xy;
        e[5]=-1.0925484305920792f*yz;
        e[6]= 0.94617469575756f*zz - 0.31539156525252f;
        e[7]=-1.0925484305920792f*xz;
        e[8]= 0.5462742152960396f*(xx-yy);
        e[9]= 0.5900435899266435f*Y*(-3.f*xx+yy);
        e[10]=2.890611442640554f*xy*Z;
        e[11]=0.4570457994644657f*Y*(1.f-5.f*zz);
        e[12]=0.3731763325901154f*Z*(5.f*zz-3.f);
        e[13]=0.4570457994644657f*X*(1.f-5.f*zz);
        e[14]=1.445305721320277f*Z*(xx-yy);
        e[15]=0.5900435899266435f*X*(-xx+3.f*yy);
        int rsw = (nl>>1)&3;
        if (quad < 2){
            uint4 v = make_uint4(pack2(e[quad*8+0], e[quad*8+1]),
                                 pack2(e[quad*8+2], e[quad*8+3]),
                                 pack2(e[quad*8+4], e[quad*8+5]),
                                 pack2(e[quad*8+6], e[quad*8+7]));
            *(uint4*)(WB + CIN_OFF + nl*64 + ((quad ^ rsw)*16)) = v;
        } else if (quad == 3){
            *(unsigned short*)(WB + CIN_OFF + nl*64 + ((3 ^ rsw)*16) + 14) = 0;  // k=31 pad
        }
    }

    const char* pW0 = ws + W0_OFF; const char* pW1 = ws + W1_OFF; const char* pW2 = ws + W2_OFF;
    const char* pC0 = ws + C0_OFF; const char* pC1 = ws + C1_OFF; const char* pC2 = ws + C2_OFF;
    const f32x4 vzero = {0.f, 0.f, 0.f, 0.f};
    float* SIGf = (float*)(WB + SIG_OFF);
    float* COLf = (float*)(WB + COL_OFF);

    #define RD_A(bp, linRow, m) \
        (*(const bf16x8*)((bp) + (linRow)*64 + ((quad ^ (((m)>>1)&3))*16)))
    #define LD_B(base, kk, NT, nt) \
        (*(const bf16x8*)((base) + (((kk)*(NT) + (nt))*64 + lane)*16))
    #define WR_H(bp, ROWS, m, kpos, val) \
        *(unsigned short*)((bp) + (((kpos)>>5)*(ROWS) + (m))*64 \
            + (((((kpos)>>3)&3) ^ (((m)>>1)&3))*16) + ((kpos)&7)*2) = f2bf(val)

    // ---- register-resident weights (loop-invariant; immune to lds_fence clobber)
    // W1: 32 frags = 128 VGPR, C1: 8 frags = 32 VGPR. LDS caps us at 2 waves/SIMD,
    // so up to 256 VGPR is free occupancy-wise.
    bf16x8 bW1[4][8];
    #pragma unroll
    for (int kk = 0; kk < 4; kk++)
        #pragma unroll
        for (int nt = 0; nt < 8; nt++)
            bW1[kk][nt] = LD_B(pW1, kk, 8, nt);
    bf16x8 bC1[2][4];
    #pragma unroll
    for (int kk = 0; kk < 2; kk++)
        #pragma unroll
        for (int nt = 0; nt < 4; nt++)
            bC1[kk][nt] = LD_B(pC1, kk, 4, nt);

    for (int half = 0; half < 2; half++){
        // ---- gather: this lane fully gathers sample p = half*64+lane ----
        {
            int p = half*64 + lane;
            float tmid = tmin + ((float)p + 0.5f) * STEP;
            float px = (ox + dx*tmid) * INV_RADIUS;
            float py = (oy + dy*tmid) * INV_RADIUS;
            float pz = (oz + dz*tmid) * INV_RADIUS;
            int x0,x1,y0,y1,z0,z1; float wx,wy,wz;
            toidx(px, 255.f, 256, x0, x1, wx);
            toidx(py, 255.f, 256, y0, y1, wy);
            toidx(pz, 255.f, 256, z0, z1, wz);
            float g1v[3];
            #pragma unroll
            for (int ch = 0; ch < 3; ch++){
                const float* gp = G1 + ch*16777216;
                int b00 = (z0*256 + y0)*256, b01 = (z0*256 + y1)*256;
                int b10 = (z1*256 + y0)*256, b11 = (z1*256 + y1)*256;
                float c000 = gp[b00+x0], c001 = gp[b00+x1];
                float c010 = gp[b01+x0], c011 = gp[b01+x1];
                float c100 = gp[b10+x0], c101 = gp[b10+x1];
                float c110 = gp[b11+x0], c111 = gp[b11+x1];
                float c00 = c000 + (c001-c000)*wx;
                float c01 = c010 + (c011-c010)*wx;
                float c10 = c100 + (c101-c100)*wx;
                float c11 = c110 + (c111-c110)*wx;
                float c0 = c00 + (c01-c00)*wy;
                float c1 = c10 + (c11-c10)*wy;
                g1v[ch] = c0 + (c1-c0)*wz;
            }
            int fx0,fx1,fy0,fy1,fz0,fz1; float fwx,fwy,fwz;
            toidx(g1v[0], 15.f, 16, fx0, fx1, fwx);
            toidx(g1v[1], 15.f, 16, fy0, fy1, fwy);
            toidx(g1v[2], 15.f, 16, fz0, fz1, fwz);
            float feats[32];
            #pragma unroll
            for (int i = 0; i < 32; i++) feats[i] = 0.f;
            const uint4* Ft = (const uint4*)(ws + FT_OFF);
            // unroll 2: max 8 uint4 loads (32 VGPRs) in flight -> bounded pressure
            #pragma unroll 2
            for (int corner = 0; corner < 8; corner++){
                int cz = (corner>>2)&1, cy = (corner>>1)&1, cx = corner&1;
                int xi = cx?fx1:fx0, yi = cy?fy1:fy0, zi = cz?fz1:fz0;
                float w = (cx?fwx:1.f-fwx) * (cy?fwy:1.f-fwy) * (cz?fwz:1.f-fwz);
                const uint4* cp = Ft + ((zi*16 + yi)*16 + xi)*4;
                #pragma unroll
                for (int q = 0; q < 4; q++){
                    uint4 v = cp[q];
                    uint32_t u[4] = {v.x, v.y, v.z, v.w};
                    #pragma unroll
                    for (int e = 0; e < 4; e++){
                        feats[q*8 + e*2    ] += w * __uint_as_float(u[e] << 16);
                        feats[q*8 + e*2 + 1] += w * __uint_as_float(u[e] & 0xFFFF0000u);
                    }
                }
            }
            int fsw = (lane>>1)&3;
            #pragma unroll
            for (int c = 0; c < 4; c++){
                uint4 v = make_uint4(pack2(feats[c*8+0], feats[c*8+1]),
                                     pack2(feats[c*8+2], feats[c*8+3]),
                                     pack2(feats[c*8+4], feats[c*8+5]),
                                     pack2(feats[c*8+6], feats[c*8+7]));
                *(uint4*)(WB + FE_OFF + lane*64 + ((c^fsw)*16)) = v;
            }
        }
        lds_fence();

        // per-half hoist of W0 (8 frags = 32 VGPR; gather temps are dead here)
        bf16x8 bW0[8];
        #pragma unroll
        for (int nt = 0; nt < 8; nt++) bW0[nt] = LD_B(pW0, 0, 8, nt);

        // ---- MLP: 4 tiles of 16 samples, wave-private, fence-ordered ----
        for (int mt = 0; mt < 4; mt++){
            const int mArow = mt*16 + nl;
            const int mW = quad*4;                       // tile-local row base
            const int gRow = half*64 + mt*16 + mW;       // ray-local sample row base

            { // L0: feats[16,32] @ W0 -> HA[16,128], relu
                bf16x8 a = RD_A(WB + FE_OFF, mArow, mArow);
                f32x4 acc[8];
                #pragma unroll
                for (int nt = 0; nt < 8; nt++)
                    acc[nt] = __builtin_amdgcn_mfma_f32_16x16x32_bf16(a, bW0[nt], vzero, 0, 0, 0);
                #pragma unroll
                for (int nt = 0; nt < 8; nt++)
                    #pragma unroll
                    for (int r = 0; r < 4; r++)
                        WR_H(WB + HA_OFF, 16, mW + r, nt*16 + nl, fmaxf(acc[nt][r], 0.f));
            }
            lds_fence();
            { // L1: HA @ W1 -> HB[16,128], relu  (W1 register-resident)
                f32x4 acc[8];
                #pragma unroll
                for (int nt = 0; nt < 8; nt++) acc[nt] = vzero;
                #pragma unroll
                for (int kk = 0; kk < 4; kk++){
                    bf16x8 a = RD_A(WB + HA_OFF, kk*16 + nl, nl);
                    #pragma unroll
                    for (int nt = 0; nt < 8; nt++)
                        acc[nt] = __builtin_amdgcn_mfma_f32_16x16x32_bf16(a, bW1[kk][nt], acc[nt], 0, 0, 0);
                }
                #pragma unroll
                for (int nt = 0; nt < 8; nt++)
                    #pragma unroll
                    for (int r = 0; r < 4; r++)
                        WR_H(WB + HB_OFF, 16, mW + r, nt*16 + nl, fmaxf(acc[nt][r], 0.f));
            }
            lds_fence();
            { // L2: HB @ W2 -> sig_out[16,16]; n=0 -> SIG, n>=1 -> CIN k=15+n
                f32x4 acc = vzero;
                #pragma unroll
                for (int kk = 0; kk < 4; kk++){
                    bf16x8 a = RD_A(WB + HB_OFF, kk*16 + nl, nl);
                    bf16x8 b = LD_B(pW2, kk, 1, 0);
                    acc = __builtin_amdgcn_mfma_f32_16x16x32_bf16(a, b, acc, 0, 0, 0);
                }
                #pragma unroll
                for (int r = 0; r < 4; r++){
                    float v = acc[r];
                    if (nl == 0) SIGf[gRow + r] = v;
                    else         WR_H(WB + CIN_OFF, 16, mW + r, 15 + nl, v);
                }
            }
            lds_fence();
            { // C0: CIN[16,32] @ Wc0 -> HA[16,64], relu
                bf16x8 a = RD_A(WB + CIN_OFF, nl, nl);
                f32x4 acc[4];
                #pragma unroll
                for (int nt = 0; nt < 4; nt++){
                    bf16x8 b = LD_B(pC0, 0, 4, nt);
                    acc[nt] = __builtin_amdgcn_mfma_f32_16x16x32_bf16(a, b, vzero, 0, 0, 0);
                }
                #pragma unroll
                for (int nt = 0; nt < 4; nt++)
                    #pragma unroll
                    for (int r = 0; r < 4; r++)
                        WR_H(WB + HA_OFF, 16, mW + r, nt*16 + nl, fmaxf(acc[nt][r], 0.f));
            }
            lds_fence();
            { // C1: HA[16,64] @ Wc1 -> HB[16,64], relu  (C1 register-resident)
                f32x4 acc[4];
                #pragma unroll
                for (int nt = 0; nt < 4; nt++) acc[nt] = vzero;
                #pragma unroll
                for (int kk = 0; kk < 2; kk++){
                    bf16x8 a = RD_A(WB + HA_OFF, kk*16 + nl, nl);
                    #pragma unroll
                    for (int nt = 0; nt < 4; nt++)
                        acc[nt] = __builtin_amdgcn_mfma_f32_16x16x32_bf16(a, bC1[kk][nt], acc[nt], 0, 0, 0);
                }
                #pragma unroll
                for (int nt = 0; nt < 4; nt++)
                    #pragma unroll
                    for (int r = 0; r < 4; r++)
                        WR_H(WB + HB_OFF, 16, mW + r, nt*16 + nl, fmaxf(acc[nt][r], 0.f));
            }
            lds_fence();
            { // C2: HB[16,64] @ Wc2 -> col[16,3]
                f32x4 acc = vzero;
                #pragma unroll
                for (int kk = 0; kk < 2; kk++){
                    bf16x8 a = RD_A(WB + HB_OFF, kk*16 + nl, nl);
                    bf16x8 b = LD_B(pC2, kk, 1, 0);
                    acc = __builtin_amdgcn_mfma_f32_16x16x32_bf16(a, b, acc, 0, 0, 0);
                }
                #pragma unroll
                for (int r = 0; r < 4; r++)
                    if (nl < 3) COLf[(gRow + r)*4 + nl] = acc[r];
            }
            lds_fence();
        }
    }

    // ---- composite: per-wave scan over 128 samples (2 per lane) ----
    float t0 = tmin + ((float)lane + 0.5f) * STEP;
    float t1 = tmin + ((float)(lane + 64) + 0.5f) * STEP;
    bool  m0 = hit && (t0 <= tmax);
    bool  m1 = hit && (t1 <= tmax);
    float sig0 = m0 ? fmaxf(SIGf[lane], 0.f) : 0.f;
    float sig1 = m1 ? fmaxf(SIGf[lane + 64], 0.f) : 0.f;
    float e0 = expf(-sig0 * STEP), e1 = expf(-sig1 * STEP);
    float al0 = 1.f - e0, al1 = 1.f - e1;
    float li0 = logf(e0 + 1e-10f), li1 = logf(e1 + 1e-10f);
    float incl0 = li0, incl1 = li1;
    #pragma unroll
    for (int off = 1; off < 64; off <<= 1){
        float v0 = __shfl_up(incl0, off);
        float v1 = __shfl_up(incl1, off);
        if (lane >= off){ incl0 += v0; incl1 += v1; }
    }
    float tot0 = __shfl(incl0, 63);
    float ex0 = incl0 - li0;
    float ex1 = tot0 + incl1 - li1;
    float w0 = al0 * expf(ex0);
    float w1 = al1 * expf(ex1);
    float r = w0 / (1.f + expf(-COLf[lane*4+0])) + w1 / (1.f + expf(-COLf[(lane+64)*4+0]));
    float g = w0 / (1.f + expf(-COLf[lane*4+1])) + w1 / (1.f + expf(-COLf[(lane+64)*4+1]));
    float b = w0 / (1.f + expf(-COLf[lane*4+2])) + w1 / (1.f + expf(-COLf[(lane+64)*4+2]));
    float wa = w0 + w1;
    #pragma unroll
    for (int off = 32; off > 0; off >>= 1){
        r  += __shfl_xor(r,  off);
        g  += __shfl_xor(g,  off);
        b  += __shfl_xor(b,  off);
        wa += __shfl_xor(wa, off);
    }
    if (lane == 0){
        out[ray*3+0] = r + (1.f - wa);
        out[ray*3+1] = g + (1.f - wa);
        out[ray*3+2] = b + (1.f - wa);
    }
}

extern "C" void kernel_launch(void* const* d_in, const int* in_sizes, int n_in,
                              void* d_out, int out_size, void* d_ws, size_t ws_size,
                              hipStream_t stream){
    const float* rays_o = (const float*)d_in[0];
    const float* rays_d = (const float*)d_in[1];
    const float* G1     = (const float*)d_in[2];
    const float* F      = (const float*)d_in[3];
    prep_f<<<16, 256, 0, stream>>>(F, (uint32_t*)d_ws);
    prep_w<<<15, 256, 0, stream>>>((const float*)d_in[4], (const float*)d_in[5],
                                   (const float*)d_in[6], (const float*)d_in[7],
                                   (const float*)d_in[8], (const float*)d_in[9],
                                   (char*)d_ws);
    nerf_fused<<<1024, 256, 0, stream>>>(rays_o, rays_d, G1, (const char*)d_ws, (float*)d_out);
}